// Round 12
// baseline (337.771 us; speedup 1.0000x reference)
//
#include <hip/hip_runtime.h>
#include <math.h>

#define NEG_SLOPE 0.2f
#define BSHIFT 8            // 256 nodes per bucket
#define MAXBUK 512          // supports N up to 131072

typedef __attribute__((ext_vector_type(8))) short short8;   // 8 bf16 (MFMA A/B frag)
typedef __attribute__((ext_vector_type(4))) float floatx4;  // MFMA C/D frag

static __device__ __forceinline__ float lrelu_exp(float e) {
    e = fmaxf(e, NEG_SLOPE * e);
    return __expf(e);
}

// fp32 -> bf16 (round-to-nearest-even)
static __device__ __forceinline__ short f2bf(float f) {
    union { float f; unsigned u; } v; v.f = f;
    unsigned r = v.u + 0x7FFFu + ((v.u >> 16) & 1u);
    return (short)(r >> 16);
}
// bf16 bits -> fp32 (exact)
static __device__ __forceinline__ float bf2f(unsigned short s) {
    union { float f; unsigned u; } v;
    v.u = ((unsigned)s) << 16;
    return v.f;
}
// packed pair of bf16 -> two fp32 (1 shift / 1 and)
static __device__ __forceinline__ float bfpair_lo(unsigned v) {
    union { float f; unsigned u; } x; x.u = v << 16; return x.f;
}
static __device__ __forceinline__ float bfpair_hi(unsigned v) {
    union { float f; unsigned u; } x; x.u = v & 0xffff0000u; return x.f;
}
// split f into hi+lo bf16 pair (covers ~16 mantissa bits)
static __device__ __forceinline__ void splitbf(float f, short& hi, short& lo) {
    hi = f2bf(f);
    lo = f2bf(f - bf2f((unsigned short)hi));
}

// ================= CSR build: LDS-bucketed partition (no global data atomics) =================

__global__ __launch_bounds__(512) void k_hist(const int* __restrict__ dst, int E, int CHUNK,
                                              int NBLK, int NBUK, int* __restrict__ blockhist) {
    __shared__ int hist[MAXBUK];
    int t = threadIdx.x, b = blockIdx.x;
    for (int i = t; i < NBUK; i += 512) hist[i] = 0;
    __syncthreads();
    int e0 = b * CHUNK, e1 = e0 + CHUNK; if (e1 > E) e1 = E;
    for (int e = e0 + t; e < e1; e += 512) atomicAdd(&hist[dst[e] >> BSHIFT], 1);
    __syncthreads();
    for (int i = t; i < NBUK; i += 512) blockhist[(size_t)i * NBLK + b] = hist[i];
}

// Per-bucket LOCAL exclusive scan across NBLK block-counts (carry loop), writes bucket total.
__global__ __launch_bounds__(256) void k_colscan(int* __restrict__ blockhist,
                                                 int* __restrict__ btot, int NBLK) {
    int bucket = blockIdx.x, t = threadIdx.x;
    int lane = t & 63, wv = t >> 6;
    __shared__ int wsum[4];
    __shared__ int carry_s;
    if (t == 0) carry_s = 0;
    __syncthreads();
    for (int base = 0; base < NBLK; base += 256) {
        int idx = base + t;
        int v = (idx < NBLK) ? blockhist[(size_t)bucket * NBLK + idx] : 0;
        int s = v;
#pragma unroll
        for (int o = 1; o < 64; o <<= 1) {
            int u = __shfl_up(s, o, 64);
            if (lane >= o) s += u;
        }
        if (lane == 63) wsum[wv] = s;
        __syncthreads();
        int b0 = 0;
#pragma unroll
        for (int w = 0; w < 4; ++w) b0 += (w < wv) ? wsum[w] : 0;
        int excl = s + b0 - v + carry_s;
        if (idx < NBLK) blockhist[(size_t)bucket * NBLK + idx] = excl;
        __syncthreads();
        if (t == 255) carry_s += s + b0;   // chunk total
        __syncthreads();
    }
    if (t == 0) btot[bucket] = carry_s;
}

// Exclusive scan over NBUK bucket totals (NBUK <= 512).
__global__ __launch_bounds__(512) void k_bucket_scan(const int* __restrict__ btot,
                                                     int* __restrict__ bucketbase, int NBUK) {
    __shared__ int sh[512];
    int t = threadIdx.x;
    int v = (t < NBUK) ? btot[t] : 0;
    sh[t] = v;
    __syncthreads();
#pragma unroll
    for (int o = 1; o < 512; o <<= 1) {
        int u = (t >= o) ? sh[t - o] : 0;
        __syncthreads();
        sh[t] += u;
        __syncthreads();
    }
    if (t < NBUK) bucketbase[t] = sh[t] - v;
    if (t == NBUK - 1) bucketbase[NBUK] = sh[t];
}

// packed record: (src << 8) | (dst & 255)   [src < 2^24; bucket id recovers dst high bits]
__global__ __launch_bounds__(512) void k_partition(const int* __restrict__ src,
                                                   const int* __restrict__ dst, int E, int CHUNK,
                                                   int NBLK, int NBUK,
                                                   const int* __restrict__ blockhist,
                                                   const int* __restrict__ bucketbase,
                                                   unsigned* __restrict__ packed) {
    __shared__ int cur[MAXBUK];
    int t = threadIdx.x, b = blockIdx.x;
    for (int i = t; i < NBUK; i += 512)
        cur[i] = blockhist[(size_t)i * NBLK + b] + bucketbase[i];
    __syncthreads();
    int e0 = b * CHUNK, e1 = e0 + CHUNK; if (e1 > E) e1 = E;
    for (int e = e0 + t; e < e1; e += 512) {
        int d = dst[e], s = src[e];
        int pos = atomicAdd(&cur[d >> BSHIFT], 1);
        packed[pos] = ((unsigned)s << 8) | ((unsigned)d & 255u);
    }
}

__global__ __launch_bounds__(256) void k_fine(const unsigned* __restrict__ packed,
                                              const int* __restrict__ bucketbase,
                                              int* __restrict__ offsets,
                                              int* __restrict__ csr_src,
                                              int N, int NBUK) {
    __shared__ int fcnt[256];
    __shared__ int wsum[4];
    int bucket = blockIdx.x, t = threadIdx.x;
    int lo = bucket << BSHIFT;
    int nn = N - lo; if (nn > 256) nn = 256;
    int ebase = bucketbase[bucket];
    int ecnt = bucketbase[bucket + 1] - ebase;
    fcnt[t] = 0;
    __syncthreads();
    for (int i = t; i < ecnt; i += 256) {
        unsigned p = packed[ebase + i];
        atomicAdd(&fcnt[p & 255u], 1);
    }
    __syncthreads();
    int v = fcnt[t];
    int lane = t & 63, wv = t >> 6;
    int s = v;
#pragma unroll
    for (int o = 1; o < 64; o <<= 1) {
        int u = __shfl_up(s, o, 64);
        if (lane >= o) s += u;
    }
    if (lane == 63) wsum[wv] = s;
    __syncthreads();
    int base = 0;
#pragma unroll
    for (int w = 0; w < 4; ++w) base += (w < wv) ? wsum[w] : 0;
    int excl = s + base - v;
    if (t < nn) offsets[lo + t] = ebase + excl;
    if (bucket == NBUK - 1 && t == 0) offsets[N] = ebase + ecnt;  // == E
    __syncthreads();
    fcnt[t] = excl;   // reuse as cursor
    __syncthreads();
    for (int i = t; i < ecnt; i += 256) {
        unsigned p = packed[ebase + i];
        int pos = atomicAdd(&fcnt[p & 255u], 1);
        csr_src[ebase + pos] = (int)(p >> 8);
    }
}

// ---------------- W2 pre-split: hi/lo bf16, padded 40 -> 48 cols ----------------
__global__ __launch_bounds__(256) void k_splitW2(const float* __restrict__ W2,
                                                 short* __restrict__ w2h,
                                                 short* __restrict__ w2l) {
    int i = blockIdx.x * 256 + threadIdx.x;
    if (i < 64 * 48) {
        int row = i / 48, col = i % 48;
        short hi = 0, lo = 0;
        if (col < 40) splitbf(W2[row * 40 + col], hi, lo);
        w2h[i] = hi; w2l[i] = lo;
    }
}

// ---------------- Layer 1 GEMM via MFMA bf16 (plain; inputs replay-constant) ----------------
__global__ __launch_bounds__(256) void k_gemm1(const float* __restrict__ x,
                                               const float* __restrict__ W1,
                                               const float* __restrict__ att_s,
                                               const float* __restrict__ att_d,
                                               unsigned short* __restrict__ h1b,
                                               float* __restrict__ a_s1,
                                               float* __restrict__ a_d1, int N) {
    int tid = threadIdx.x, wave = tid >> 6, lane = tid & 63;
    int n16 = lane & 15, q = lane >> 4;
    int nb = blockIdx.x * 64 + wave * 16;
    if (nb >= N) return;

    short8 bfr[4][4];
#pragma unroll
    for (int ct = 0; ct < 4; ++ct) {
        int n = ct * 16 + n16;
#pragma unroll
        for (int kc = 0; kc < 4; ++kc) {
            int k0 = kc * 32 + q * 8;
            short8 b;
#pragma unroll
            for (int j = 0; j < 8; ++j) b[j] = f2bf(W1[(k0 + j) * 64 + n]);
            bfr[ct][kc] = b;
        }
    }

    int arow = nb + n16; if (arow >= N) arow = N - 1;
    const float* xr = x + (size_t)arow * 128 + q * 8;
    short8 afr[4];
#pragma unroll
    for (int kc = 0; kc < 4; ++kc) {
        float4 u0 = *(const float4*)(xr + kc * 32);
        float4 u1 = *(const float4*)(xr + kc * 32 + 4);
        short8 a;
        a[0] = f2bf(u0.x); a[1] = f2bf(u0.y); a[2] = f2bf(u0.z); a[3] = f2bf(u0.w);
        a[4] = f2bf(u1.x); a[5] = f2bf(u1.y); a[6] = f2bf(u1.z); a[7] = f2bf(u1.w);
        afr[kc] = a;
    }

    floatx4 acc[4];
#pragma unroll
    for (int ct = 0; ct < 4; ++ct) {
        floatx4 c = {0.f, 0.f, 0.f, 0.f};
#pragma unroll
        for (int kc = 0; kc < 4; ++kc)
            c = __builtin_amdgcn_mfma_f32_16x16x32_bf16(afr[kc], bfr[ct][kc], c, 0, 0, 0);
        acc[ct] = c;
    }

#pragma unroll
    for (int ct = 0; ct < 4; ++ct) {
#pragma unroll
        for (int r = 0; r < 4; ++r) {
            int row = nb + q * 4 + r;
            if (row < N) h1b[(size_t)row * 64 + ct * 16 + n16] = (unsigned short)f2bf(acc[ct][r]);
        }
    }

#pragma unroll
    for (int ct = 0; ct < 4; ++ct) {
        float as = att_s[ct * 16 + n16];
        float ad = att_d[ct * 16 + n16];
#pragma unroll
        for (int r = 0; r < 4; ++r) {
            float ps = acc[ct][r] * as;
            float pd = acc[ct][r] * ad;
#pragma unroll
            for (int m = 1; m < 8; m <<= 1) {
                ps += __shfl_xor(ps, m, 64);
                pd += __shfl_xor(pd, m, 64);
            }
            int row = nb + q * 4 + r;
            if ((n16 & 7) == 0 && row < N) {
                int h = 2 * ct + (n16 >> 3);
                a_s1[row * 8 + h] = ps;
                a_d1[row * 8 + h] = pd;
            }
        }
    }
}

// ---------------- Layer 1 aggregation: R9 pair-scheme + deduplicated edge weights ------------
// fma role:    lane = (q2 = lane>>5, c = lane&31): edge-half q2, channel pair 2c/2c+1, head c>>2.
// weight role: lane = (es = lane>>3, hw = lane&7): per 64-edge chunk, lane computes the weight
//              of edge 8r+es for head hw (r=0..7) — each (edge,head) exp computed exactly ONCE
//              (was 4x redundant); broadcast to fma lanes via one bpermute per u-step.
__global__ __launch_bounds__(256) void k_agg1(const unsigned short* __restrict__ h1b,
                                              const float* __restrict__ a_s1,
                                              const float* __restrict__ a_d1,
                                              const int* __restrict__ offsets,
                                              const int* __restrict__ csr_src,
                                              const float* __restrict__ b1,
                                              float* __restrict__ y1, int N) {
    int wave = threadIdx.x >> 6, lane = threadIdx.x & 63;
    int d = blockIdx.x * 4 + wave;
    if (d >= N) return;
    int q2 = lane >> 5;          // fma: which edge of the pair
    int c  = lane & 31;          // fma: channel pair 2c, 2c+1
    int hc = c >> 2;             // fma: head
    int es = lane >> 3;          // weight: edge slot 0..7
    int hw = lane & 7;           // weight: head 0..7
    float ad_w = a_d1[d * 8 + hw];
    float accx = 0.f, accy = 0.f;
    float wsum_eh = 0.f;         // per-(head hw) sum over this lane's edge slots
    // self-loop: weight counted once per head in weight layout; fma on half 0
    if (es == 0) wsum_eh = lrelu_exp(a_s1[d * 8 + hw] + ad_w);
    if (q2 == 0) {
        float w0 = lrelu_exp(a_s1[d * 8 + hc] + a_d1[d * 8 + hc]);
        unsigned v = *(const unsigned*)(h1b + (size_t)d * 64 + 2 * c);
        accx = w0 * bfpair_lo(v);
        accy = w0 * bfpair_hi(v);
    }
    int i0 = offsets[d], i1 = offsets[d + 1];
    for (int base = i0; base < i1; base += 64) {
        int m = i1 - base; if (m > 64) m = 64;
        int sv = (lane < m) ? csr_src[base + lane] : 0;
        // ---- weight precompute: 8 loads + 8 exps per 64 edges (no redundancy) ----
        float w[8];
        {
            int se[8];
#pragma unroll
            for (int r = 0; r < 8; ++r) se[r] = __shfl(sv, 8 * r + es, 64);
            float ev[8];
#pragma unroll
            for (int r = 0; r < 8; ++r) ev[r] = a_s1[se[r] * 8 + hw] + ad_w;
#pragma unroll
            for (int r = 0; r < 8; ++r) {
                w[r] = (8 * r + es < m) ? lrelu_exp(ev[r]) : 0.f;
                wsum_eh += w[r];
            }
        }
        // ---- fma role: 16 edges per sub-chunk; weights arrive by bpermute ----
#pragma unroll
        for (int jj = 0; jj < 4; ++jj) {
            int j = jj * 16;
            if (j < m) {                                   // wave-uniform branch
                int si[8]; float wq[8]; unsigned vv[8];
#pragma unroll
                for (int u = 0; u < 8; ++u) si[u] = __shfl(sv, j + 2 * u + q2, 64);
#pragma unroll
                for (int u = 0; u < 8; ++u)
                    wq[u] = __shfl(w[2 * jj + (u >> 2)], (((2 * u + q2) & 7) << 3) + hc, 64);
#pragma unroll
                for (int u = 0; u < 8; ++u)
                    vv[u] = *(const unsigned*)(h1b + (size_t)si[u] * 64 + 2 * c);
#pragma unroll
                for (int u = 0; u < 8; ++u) {
                    accx = fmaf(wq[u], bfpair_lo(vv[u]), accx);
                    accy = fmaf(wq[u], bfpair_hi(vv[u]), accy);
                }
            }
        }
    }
    // finalize wsum: sum over edge slots (lane bits 3..5), then fetch own head's total
#pragma unroll
    for (int s = 8; s < 64; s <<= 1) wsum_eh += __shfl_xor(wsum_eh, s, 64);
    float wsum = __shfl(wsum_eh, hc, 64);
    // combine the two edge halves of the fma role
    accx += __shfl_xor(accx, 32, 64);
    accy += __shfl_xor(accy, 32, 64);
    if (q2 == 0) {
        float inv = 1.f / (wsum + 1e-16f);
        float ox = accx * inv + b1[2 * c];
        float oy = accy * inv + b1[2 * c + 1];
        ox = ox > 0.f ? ox : expm1f(ox);
        oy = oy > 0.f ? oy : expm1f(oy);
        float2 o2 = make_float2(ox, oy);
        *(float2*)(y1 + (size_t)d * 64 + 2 * c) = o2;   // fp32 (precision-critical)
    }
}

// ---------------- Layer 2 GEMM, split-bf16 (y1 replay-variant -> fp32-class needed) ----------
__global__ __launch_bounds__(256) void k_gemm2(const float* __restrict__ y1,
                                               const short* __restrict__ w2h,
                                               const short* __restrict__ w2l,
                                               const float* __restrict__ att_s,
                                               const float* __restrict__ att_d,
                                               unsigned short* __restrict__ h2b,
                                               float* __restrict__ a2s,
                                               float* __restrict__ a2d, int N) {
    int tid = threadIdx.x, wave = tid >> 6, lane = tid & 63;
    int n16 = lane & 15, q = lane >> 4;
    int nb = blockIdx.x * 64 + wave * 16;
    if (nb >= N) return;

    int arow = nb + n16; if (arow >= N) arow = N - 1;
    const float* yr = y1 + (size_t)arow * 64 + q * 8;
    short8 ah[2], al[2];
#pragma unroll
    for (int kc = 0; kc < 2; ++kc) {
        float4 u0 = *(const float4*)(yr + kc * 32);
        float4 u1 = *(const float4*)(yr + kc * 32 + 4);
        short8 h, l; short hi, lo;
        splitbf(u0.x, hi, lo); h[0] = hi; l[0] = lo;
        splitbf(u0.y, hi, lo); h[1] = hi; l[1] = lo;
        splitbf(u0.z, hi, lo); h[2] = hi; l[2] = lo;
        splitbf(u0.w, hi, lo); h[3] = hi; l[3] = lo;
        splitbf(u1.x, hi, lo); h[4] = hi; l[4] = lo;
        splitbf(u1.y, hi, lo); h[5] = hi; l[5] = lo;
        splitbf(u1.z, hi, lo); h[6] = hi; l[6] = lo;
        splitbf(u1.w, hi, lo); h[7] = hi; l[7] = lo;
        ah[kc] = h; al[kc] = l;
    }

    float psr[4] = {0.f, 0.f, 0.f, 0.f}, pdr[4] = {0.f, 0.f, 0.f, 0.f};
#pragma unroll
    for (int ct = 0; ct < 3; ++ct) {
        int n = ct * 16 + n16;
        short8 bh0, bh1, bl0, bl1;
#pragma unroll
        for (int j = 0; j < 8; ++j) {
            int k0 = q * 8 + j;
            bh0[j] = w2h[k0 * 48 + n];
            bl0[j] = w2l[k0 * 48 + n];
            bh1[j] = w2h[(32 + k0) * 48 + n];
            bl1[j] = w2l[(32 + k0) * 48 + n];
        }
        floatx4 c = {0.f, 0.f, 0.f, 0.f};
        c = __builtin_amdgcn_mfma_f32_16x16x32_bf16(ah[0], bl0, c, 0, 0, 0);
        c = __builtin_amdgcn_mfma_f32_16x16x32_bf16(al[0], bh0, c, 0, 0, 0);
        c = __builtin_amdgcn_mfma_f32_16x16x32_bf16(ah[0], bh0, c, 0, 0, 0);
        c = __builtin_amdgcn_mfma_f32_16x16x32_bf16(ah[1], bl1, c, 0, 0, 0);
        c = __builtin_amdgcn_mfma_f32_16x16x32_bf16(al[1], bh1, c, 0, 0, 0);
        c = __builtin_amdgcn_mfma_f32_16x16x32_bf16(ah[1], bh1, c, 0, 0, 0);

        int col = ct * 16 + n16;
#pragma unroll
        for (int r = 0; r < 4; ++r) {
            int row = nb + q * 4 + r;
            if (col < 40 && row < N) h2b[(size_t)row * 40 + col] = (unsigned short)f2bf(c[r]);
        }
        float asv = (col < 40) ? att_s[col] : 0.f;
        float adv = (col < 40) ? att_d[col] : 0.f;
#pragma unroll
        for (int r = 0; r < 4; ++r) {
            psr[r] = fmaf(c[r], asv, psr[r]);
            pdr[r] = fmaf(c[r], adv, pdr[r]);
        }
    }
#pragma unroll
    for (int r = 0; r < 4; ++r) {
        float ps = psr[r], pd = pdr[r];
#pragma unroll
        for (int m = 1; m < 16; m <<= 1) {
            ps += __shfl_xor(ps, m, 64);
            pd += __shfl_xor(pd, m, 64);
        }
        int row = nb + q * 4 + r;
        if (n16 == 0 && row < N) { a2s[row] = ps; a2d[row] = pd; }
    }
}

// ---------------- Layer 2 aggregation: 3 edges per gather instr + log_softmax ----------------
__global__ __launch_bounds__(256) void k_agg2(const unsigned short* __restrict__ h2b,
                                              const float* __restrict__ a2s,
                                              const float* __restrict__ a2d,
                                              const int* __restrict__ offsets,
                                              const int* __restrict__ csr_src,
                                              const float* __restrict__ b2,
                                              float* __restrict__ out, int N) {
    int wave = threadIdx.x >> 6, lane = threadIdx.x & 63;
    int d = blockIdx.x * 4 + wave;
    if (d >= N) return;
    int t = lane / 20;          // 0..2 active thirds (3 = idle tail lanes 60..63)
    int c = lane % 20;          // channel pair: 2c, 2c+1
    float ad = a2d[d];
    float w0 = lrelu_exp(a2s[d] + ad);
    float accx = 0.f, accy = 0.f;
    if (t == 0) {               // self-loop on third 0
        unsigned v = *(const unsigned*)(h2b + (size_t)d * 40 + 2 * c);
        accx = w0 * bfpair_lo(v);
        accy = w0 * bfpair_hi(v);
    }
    float wsum_l = 0.f;
    int i0 = offsets[d], i1 = offsets[d + 1];
    for (int base = i0; base < i1; base += 48) {
        int m = i1 - base; if (m > 48) m = 48;
        int sv = 0; float wv = 0.f;
        if (lane < m) {
            sv = csr_src[base + lane];
            wv = lrelu_exp(a2s[sv] + ad);
        }
        wsum_l += wv;
        for (int j = 0; j < m; j += 24) {
            int si[8]; float wq[8]; unsigned vv[8];
#pragma unroll
            for (int u = 0; u < 8; ++u) {
                int e = j + 3 * u + t;
                si[u] = __shfl(sv, e, 64);
                wq[u] = __shfl(wv, e, 64);
            }
#pragma unroll
            for (int u = 0; u < 8; ++u)
                vv[u] = *(const unsigned*)(h2b + (size_t)si[u] * 40 + 2 * c);
#pragma unroll
            for (int u = 0; u < 8; ++u) {
                accx = fmaf(wq[u], bfpair_lo(vv[u]), accx);
                accy = fmaf(wq[u], bfpair_hi(vv[u]), accy);
            }
        }
    }
    accx += __shfl(accx, lane + 20, 64) + __shfl(accx, lane + 40, 64);
    accy += __shfl(accy, lane + 20, 64) + __shfl(accy, lane + 40, 64);
#pragma unroll
    for (int mm = 1; mm < 64; mm <<= 1) wsum_l += __shfl_xor(wsum_l, mm, 64);
    float wsum = wsum_l + w0;
    bool act = (lane < 20);
    float inv = 1.f / (wsum + 1e-16f);
    float ox = act ? (accx * inv + b2[2 * c]) : -INFINITY;
    float oy = act ? (accy * inv + b2[2 * c + 1]) : -INFINITY;
    float mx = fmaxf(ox, oy);
#pragma unroll
    for (int mm = 1; mm < 64; mm <<= 1) mx = fmaxf(mx, __shfl_xor(mx, mm, 64));
    float ex = act ? (__expf(ox - mx) + __expf(oy - mx)) : 0.f;
#pragma unroll
    for (int mm = 1; mm < 64; mm <<= 1) ex += __shfl_xor(ex, mm, 64);
    if (act) {
        float lse = __logf(ex);
        float2 o2 = make_float2(ox - mx - lse, oy - mx - lse);
        *(float2*)(out + (size_t)d * 40 + 2 * c) = o2;
    }
}

// ---------------- launcher ----------------

extern "C" void kernel_launch(void* const* d_in, const int* in_sizes, int n_in,
                              void* d_out, int out_size, void* d_ws, size_t ws_size,
                              hipStream_t stream) {
    const float* x   = (const float*)d_in[0];
    const int*   ei  = (const int*)d_in[1];
    const float* W1  = (const float*)d_in[2];
    const float* as1 = (const float*)d_in[3];
    const float* ad1 = (const float*)d_in[4];
    const float* b1  = (const float*)d_in[5];
    const float* W2  = (const float*)d_in[6];
    const float* as2 = (const float*)d_in[7];
    const float* ad2 = (const float*)d_in[8];
    const float* b2  = (const float*)d_in[9];
    float* out = (float*)d_out;

    int N = in_sizes[0] / 128;   // 100000
    int E = in_sizes[1] / 2;     // 1600000
    const int* src = ei;
    const int* dst = ei + E;

    int NBUK = (N + 255) >> BSHIFT;          // 391
    int CHUNK = 4096;
    int NBLK = (E + CHUNK - 1) / CHUNK;      // 391

    char* ws = (char*)d_ws;
    size_t off = 0;
    auto alloc = [&](size_t bytes) -> char* {
        char* p = ws + off;
        off += (bytes + 255) & ~(size_t)255;
        return p;
    };
    unsigned short* h1b = (unsigned short*)alloc((size_t)N * 64 * 2);   // bf16
    float* a_s1    = (float*)alloc((size_t)N * 8 * 4);
    float* a_d1    = (float*)alloc((size_t)N * 8 * 4);
    float* y1      = (float*)alloc((size_t)N * 64 * 4);                 // fp32 (precision-critical)
    // h2b (bf16, 8 MB) and packed (uint, 6.4 MB) are temporally disjoint: share region.
    size_t shared_sz = (size_t)N * 40 * 2;
    if ((size_t)E * 4 > shared_sz) shared_sz = (size_t)E * 4;
    char*  region  = alloc(shared_sz);
    unsigned short* h2b = (unsigned short*)region;
    unsigned* packed    = (unsigned*)region;
    float* a2s     = (float*)alloc((size_t)N * 4);
    float* a2d     = (float*)alloc((size_t)N * 4);
    int*   offsets = (int*)alloc((size_t)(N + 1) * 4);
    int*   csr_src = (int*)alloc((size_t)E * 4);
    int*   blockhist  = (int*)alloc((size_t)NBUK * NBLK * 4);
    int*   btot       = (int*)alloc((size_t)NBUK * 4);
    int*   bucketbase = (int*)alloc((size_t)(NBUK + 1) * 4);
    short* w2h     = (short*)alloc((size_t)64 * 48 * 2);
    short* w2l     = (short*)alloc((size_t)64 * 48 * 2);

    int nb = (N + 3) / 4;
    int gb = (N + 63) / 64;

    k_hist<<<NBLK, 512, 0, stream>>>(dst, E, CHUNK, NBLK, NBUK, blockhist);
    k_colscan<<<NBUK, 256, 0, stream>>>(blockhist, btot, NBLK);
    k_bucket_scan<<<1, 512, 0, stream>>>(btot, bucketbase, NBUK);
    k_partition<<<NBLK, 512, 0, stream>>>(src, dst, E, CHUNK, NBLK, NBUK, blockhist,
                                          bucketbase, packed);
    k_fine<<<NBUK, 256, 0, stream>>>(packed, bucketbase, offsets, csr_src, N, NBUK);
    k_splitW2<<<12, 256, 0, stream>>>(W2, w2h, w2l);
    k_gemm1<<<gb, 256, 0, stream>>>(x, W1, as1, ad1, h1b, a_s1, a_d1, N);
    k_agg1<<<nb, 256, 0, stream>>>(h1b, a_s1, a_d1, offsets, csr_src, b1, y1, N);
    k_gemm2<<<gb, 256, 0, stream>>>(y1, w2h, w2l, as2, ad2, h2b, a2s, a2d, N);
    k_agg2<<<nb, 256, 0, stream>>>(h2b, a2s, a2d, offsets, csr_src, b2, out, N);
}

// Round 13
// 293.443 us; speedup vs baseline: 1.1511x; 1.1511x over previous
//
#include <hip/hip_runtime.h>
#include <math.h>

#define NEG_SLOPE 0.2f
#define BSHIFT 8            // 256 nodes per bucket
#define MAXBUK 512          // supports N up to 131072

typedef __attribute__((ext_vector_type(8))) short short8;   // 8 bf16 (MFMA A/B frag)
typedef __attribute__((ext_vector_type(4))) float floatx4;  // MFMA C/D frag

static __device__ __forceinline__ float lrelu_exp(float e) {
    e = fmaxf(e, NEG_SLOPE * e);
    return __expf(e);
}

// fp32 -> bf16 (round-to-nearest-even)
static __device__ __forceinline__ short f2bf(float f) {
    union { float f; unsigned u; } v; v.f = f;
    unsigned r = v.u + 0x7FFFu + ((v.u >> 16) & 1u);
    return (short)(r >> 16);
}
// bf16 bits -> fp32 (exact)
static __device__ __forceinline__ float bf2f(unsigned short s) {
    union { float f; unsigned u; } v;
    v.u = ((unsigned)s) << 16;
    return v.f;
}
// packed pair of bf16 -> two fp32 (1 shift / 1 and)
static __device__ __forceinline__ float bfpair_lo(unsigned v) {
    union { float f; unsigned u; } x; x.u = v << 16; return x.f;
}
static __device__ __forceinline__ float bfpair_hi(unsigned v) {
    union { float f; unsigned u; } x; x.u = v & 0xffff0000u; return x.f;
}
// split f into hi+lo bf16 pair (covers ~16 mantissa bits)
static __device__ __forceinline__ void splitbf(float f, short& hi, short& lo) {
    hi = f2bf(f);
    lo = f2bf(f - bf2f((unsigned short)hi));
}

// ================= CSR build: LDS-bucketed partition (no global data atomics) =================

__global__ __launch_bounds__(512) void k_hist(const int* __restrict__ dst, int E, int CHUNK,
                                              int NBLK, int NBUK, int* __restrict__ blockhist) {
    __shared__ int hist[MAXBUK];
    int t = threadIdx.x, b = blockIdx.x;
    for (int i = t; i < NBUK; i += 512) hist[i] = 0;
    __syncthreads();
    int e0 = b * CHUNK, e1 = e0 + CHUNK; if (e1 > E) e1 = E;
    for (int e = e0 + t; e < e1; e += 512) atomicAdd(&hist[dst[e] >> BSHIFT], 1);
    __syncthreads();
    for (int i = t; i < NBUK; i += 512) blockhist[(size_t)i * NBLK + b] = hist[i];
}

// Per-bucket LOCAL exclusive scan across NBLK block-counts (carry loop), writes bucket total.
__global__ __launch_bounds__(256) void k_colscan(int* __restrict__ blockhist,
                                                 int* __restrict__ btot, int NBLK) {
    int bucket = blockIdx.x, t = threadIdx.x;
    int lane = t & 63, wv = t >> 6;
    __shared__ int wsum[4];
    __shared__ int carry_s;
    if (t == 0) carry_s = 0;
    __syncthreads();
    for (int base = 0; base < NBLK; base += 256) {
        int idx = base + t;
        int v = (idx < NBLK) ? blockhist[(size_t)bucket * NBLK + idx] : 0;
        int s = v;
#pragma unroll
        for (int o = 1; o < 64; o <<= 1) {
            int u = __shfl_up(s, o, 64);
            if (lane >= o) s += u;
        }
        if (lane == 63) wsum[wv] = s;
        __syncthreads();
        int b0 = 0;
#pragma unroll
        for (int w = 0; w < 4; ++w) b0 += (w < wv) ? wsum[w] : 0;
        int excl = s + b0 - v + carry_s;
        if (idx < NBLK) blockhist[(size_t)bucket * NBLK + idx] = excl;
        __syncthreads();
        if (t == 255) carry_s += s + b0;   // chunk total
        __syncthreads();
    }
    if (t == 0) btot[bucket] = carry_s;
}

// Exclusive scan over NBUK bucket totals (NBUK <= 512).
__global__ __launch_bounds__(512) void k_bucket_scan(const int* __restrict__ btot,
                                                     int* __restrict__ bucketbase, int NBUK) {
    __shared__ int sh[512];
    int t = threadIdx.x;
    int v = (t < NBUK) ? btot[t] : 0;
    sh[t] = v;
    __syncthreads();
#pragma unroll
    for (int o = 1; o < 512; o <<= 1) {
        int u = (t >= o) ? sh[t - o] : 0;
        __syncthreads();
        sh[t] += u;
        __syncthreads();
    }
    if (t < NBUK) bucketbase[t] = sh[t] - v;
    if (t == NBUK - 1) bucketbase[NBUK] = sh[t];
}

// packed record: (src << 8) | (dst & 255)   [src < 2^24; bucket id recovers dst high bits]
__global__ __launch_bounds__(512) void k_partition(const int* __restrict__ src,
                                                   const int* __restrict__ dst, int E, int CHUNK,
                                                   int NBLK, int NBUK,
                                                   const int* __restrict__ blockhist,
                                                   const int* __restrict__ bucketbase,
                                                   unsigned* __restrict__ packed) {
    __shared__ int cur[MAXBUK];
    int t = threadIdx.x, b = blockIdx.x;
    for (int i = t; i < NBUK; i += 512)
        cur[i] = blockhist[(size_t)i * NBLK + b] + bucketbase[i];
    __syncthreads();
    int e0 = b * CHUNK, e1 = e0 + CHUNK; if (e1 > E) e1 = E;
    for (int e = e0 + t; e < e1; e += 512) {
        int d = dst[e], s = src[e];
        int pos = atomicAdd(&cur[d >> BSHIFT], 1);
        packed[pos] = ((unsigned)s << 8) | ((unsigned)d & 255u);
    }
}

// R13: 512 threads (was 256) — 391 blocks x 8 waves doubles outstanding latency chains/CU.
// fcnt histogram/cursor stays 256 entries; scan phase uses threads 0..255 only.
__global__ __launch_bounds__(512) void k_fine(const unsigned* __restrict__ packed,
                                              const int* __restrict__ bucketbase,
                                              int* __restrict__ offsets,
                                              int* __restrict__ csr_src,
                                              int N, int NBUK) {
    __shared__ int fcnt[256];
    __shared__ int wsum[4];
    int bucket = blockIdx.x, t = threadIdx.x;
    int lo = bucket << BSHIFT;
    int nn = N - lo; if (nn > 256) nn = 256;
    int ebase = bucketbase[bucket];
    int ecnt = bucketbase[bucket + 1] - ebase;
    if (t < 256) fcnt[t] = 0;
    __syncthreads();
    for (int i = t; i < ecnt; i += 512) {
        unsigned p = packed[ebase + i];
        atomicAdd(&fcnt[p & 255u], 1);
    }
    __syncthreads();
    int lane = t & 63, wv = t >> 6;
    int v = 0, s = 0;
    if (t < 256) {
        v = fcnt[t];
        s = v;
#pragma unroll
        for (int o = 1; o < 64; o <<= 1) {
            int u = __shfl_up(s, o, 64);
            if (lane >= o) s += u;
        }
        if (lane == 63) wsum[wv] = s;
    }
    __syncthreads();
    int excl = 0;
    if (t < 256) {
        int base = 0;
#pragma unroll
        for (int w = 0; w < 4; ++w) base += (w < wv) ? wsum[w] : 0;
        excl = s + base - v;
        if (t < nn) offsets[lo + t] = ebase + excl;
    }
    if (bucket == NBUK - 1 && t == 0) offsets[N] = ebase + ecnt;  // == E
    __syncthreads();
    if (t < 256) fcnt[t] = excl;   // reuse as cursor
    __syncthreads();
    for (int i = t; i < ecnt; i += 512) {
        unsigned p = packed[ebase + i];
        int pos = atomicAdd(&fcnt[p & 255u], 1);
        csr_src[ebase + pos] = (int)(p >> 8);
    }
}

// ---------------- W2 pre-split: hi/lo bf16, padded 40 -> 48 cols ----------------
__global__ __launch_bounds__(256) void k_splitW2(const float* __restrict__ W2,
                                                 short* __restrict__ w2h,
                                                 short* __restrict__ w2l) {
    int i = blockIdx.x * 256 + threadIdx.x;
    if (i < 64 * 48) {
        int row = i / 48, col = i % 48;
        short hi = 0, lo = 0;
        if (col < 40) splitbf(W2[row * 40 + col], hi, lo);
        w2h[i] = hi; w2l[i] = lo;
    }
}

// ---------------- Layer 1 GEMM via MFMA bf16 (plain; inputs replay-constant) ----------------
__global__ __launch_bounds__(256) void k_gemm1(const float* __restrict__ x,
                                               const float* __restrict__ W1,
                                               const float* __restrict__ att_s,
                                               const float* __restrict__ att_d,
                                               unsigned short* __restrict__ h1b,
                                               float* __restrict__ a_s1,
                                               float* __restrict__ a_d1, int N) {
    int tid = threadIdx.x, wave = tid >> 6, lane = tid & 63;
    int n16 = lane & 15, q = lane >> 4;
    int nb = blockIdx.x * 64 + wave * 16;
    if (nb >= N) return;

    short8 bfr[4][4];
#pragma unroll
    for (int ct = 0; ct < 4; ++ct) {
        int n = ct * 16 + n16;
#pragma unroll
        for (int kc = 0; kc < 4; ++kc) {
            int k0 = kc * 32 + q * 8;
            short8 b;
#pragma unroll
            for (int j = 0; j < 8; ++j) b[j] = f2bf(W1[(k0 + j) * 64 + n]);
            bfr[ct][kc] = b;
        }
    }

    int arow = nb + n16; if (arow >= N) arow = N - 1;
    const float* xr = x + (size_t)arow * 128 + q * 8;
    short8 afr[4];
#pragma unroll
    for (int kc = 0; kc < 4; ++kc) {
        float4 u0 = *(const float4*)(xr + kc * 32);
        float4 u1 = *(const float4*)(xr + kc * 32 + 4);
        short8 a;
        a[0] = f2bf(u0.x); a[1] = f2bf(u0.y); a[2] = f2bf(u0.z); a[3] = f2bf(u0.w);
        a[4] = f2bf(u1.x); a[5] = f2bf(u1.y); a[6] = f2bf(u1.z); a[7] = f2bf(u1.w);
        afr[kc] = a;
    }

    floatx4 acc[4];
#pragma unroll
    for (int ct = 0; ct < 4; ++ct) {
        floatx4 c = {0.f, 0.f, 0.f, 0.f};
#pragma unroll
        for (int kc = 0; kc < 4; ++kc)
            c = __builtin_amdgcn_mfma_f32_16x16x32_bf16(afr[kc], bfr[ct][kc], c, 0, 0, 0);
        acc[ct] = c;
    }

#pragma unroll
    for (int ct = 0; ct < 4; ++ct) {
#pragma unroll
        for (int r = 0; r < 4; ++r) {
            int row = nb + q * 4 + r;
            if (row < N) h1b[(size_t)row * 64 + ct * 16 + n16] = (unsigned short)f2bf(acc[ct][r]);
        }
    }

#pragma unroll
    for (int ct = 0; ct < 4; ++ct) {
        float as = att_s[ct * 16 + n16];
        float ad = att_d[ct * 16 + n16];
#pragma unroll
        for (int r = 0; r < 4; ++r) {
            float ps = acc[ct][r] * as;
            float pd = acc[ct][r] * ad;
#pragma unroll
            for (int m = 1; m < 8; m <<= 1) {
                ps += __shfl_xor(ps, m, 64);
                pd += __shfl_xor(pd, m, 64);
            }
            int row = nb + q * 4 + r;
            if ((n16 & 7) == 0 && row < N) {
                int h = 2 * ct + (n16 >> 3);
                a_s1[row * 8 + h] = ps;
                a_d1[row * 8 + h] = pd;
            }
        }
    }
}

// ---------------- Layer 1 aggregation: R9 pair-scheme — FROZEN ------------------------------
// Measured local optimum (63.6 us): VALUBusy 88% @ occupancy 70%, ~84% of the ~53 us
// random-gather service floor (149 MB HBM + ~70 MB L2 at ~3.4 TB/s combined).
// R10 (8-ch/lane, fewer shfl) -> 81 us; R12 (dedup exp via bpermute, VGPR 52, occ 40%)
// -> 106 us. Do not restructure without disasm evidence.
__global__ __launch_bounds__(256) void k_agg1(const unsigned short* __restrict__ h1b,
                                              const float* __restrict__ a_s1,
                                              const float* __restrict__ a_d1,
                                              const int* __restrict__ offsets,
                                              const int* __restrict__ csr_src,
                                              const float* __restrict__ b1,
                                              float* __restrict__ y1, int N) {
    int wave = threadIdx.x >> 6, lane = threadIdx.x & 63;
    int d = blockIdx.x * 4 + wave;
    if (d >= N) return;
    int q2 = lane >> 5;          // which edge of the pair
    int c  = lane & 31;          // channel pair: 2c, 2c+1
    int h  = c >> 2;             // head (same for both channels)
    float ad = a_d1[d * 8 + h];
    float accx = 0.f, accy = 0.f;
    float wsum_l = 0.f;
    if (q2 == 0) {               // self-loop on half 0
        float w0 = lrelu_exp(a_s1[d * 8 + h] + ad);
        unsigned v = *(const unsigned*)(h1b + (size_t)d * 64 + 2 * c);
        accx = w0 * bfpair_lo(v);
        accy = w0 * bfpair_hi(v);
        wsum_l = w0;
    }
    int i0 = offsets[d], i1 = offsets[d + 1];
    for (int base = i0; base < i1; base += 64) {
        int m = i1 - base; if (m > 64) m = 64;
        int sv = (lane < m) ? csr_src[base + lane] : 0;
        for (int j = 0; j < m; j += 16) {
            int   ei[8]; int si[8]; float ev[8]; unsigned vv[8];
#pragma unroll
            for (int u = 0; u < 8; ++u) {
                ei[u] = j + 2 * u + q2;
                si[u] = __shfl(sv, ei[u], 64);
            }
#pragma unroll
            for (int u = 0; u < 8; ++u) ev[u] = a_s1[si[u] * 8 + h] + ad;
#pragma unroll
            for (int u = 0; u < 8; ++u)
                vv[u] = *(const unsigned*)(h1b + (size_t)si[u] * 64 + 2 * c);
#pragma unroll
            for (int u = 0; u < 8; ++u) {
                float w = (ei[u] < m) ? lrelu_exp(ev[u]) : 0.f;
                wsum_l += w;
                accx = fmaf(w, bfpair_lo(vv[u]), accx);
                accy = fmaf(w, bfpair_hi(vv[u]), accy);
            }
        }
    }
    // combine the two halves (edges were split across halves; channels identical)
    accx += __shfl_xor(accx, 32, 64);
    accy += __shfl_xor(accy, 32, 64);
    wsum_l += __shfl_xor(wsum_l, 32, 64);
    if (q2 == 0) {
        float inv = 1.f / (wsum_l + 1e-16f);
        float bx = b1[2 * c], by = b1[2 * c + 1];
        float ox = accx * inv + bx;
        float oy = accy * inv + by;
        ox = ox > 0.f ? ox : expm1f(ox);
        oy = oy > 0.f ? oy : expm1f(oy);
        float2 o2 = make_float2(ox, oy);
        *(float2*)(y1 + (size_t)d * 64 + 2 * c) = o2;   // fp32 (precision-critical)
    }
}

// ---------------- Layer 2 GEMM, split-bf16 (y1 replay-variant -> fp32-class needed) ----------
__global__ __launch_bounds__(256) void k_gemm2(const float* __restrict__ y1,
                                               const short* __restrict__ w2h,
                                               const short* __restrict__ w2l,
                                               const float* __restrict__ att_s,
                                               const float* __restrict__ att_d,
                                               unsigned short* __restrict__ h2b,
                                               float* __restrict__ a2s,
                                               float* __restrict__ a2d, int N) {
    int tid = threadIdx.x, wave = tid >> 6, lane = tid & 63;
    int n16 = lane & 15, q = lane >> 4;
    int nb = blockIdx.x * 64 + wave * 16;
    if (nb >= N) return;

    int arow = nb + n16; if (arow >= N) arow = N - 1;
    const float* yr = y1 + (size_t)arow * 64 + q * 8;
    short8 ah[2], al[2];
#pragma unroll
    for (int kc = 0; kc < 2; ++kc) {
        float4 u0 = *(const float4*)(yr + kc * 32);
        float4 u1 = *(const float4*)(yr + kc * 32 + 4);
        short8 h, l; short hi, lo;
        splitbf(u0.x, hi, lo); h[0] = hi; l[0] = lo;
        splitbf(u0.y, hi, lo); h[1] = hi; l[1] = lo;
        splitbf(u0.z, hi, lo); h[2] = hi; l[2] = lo;
        splitbf(u0.w, hi, lo); h[3] = hi; l[3] = lo;
        splitbf(u1.x, hi, lo); h[4] = hi; l[4] = lo;
        splitbf(u1.y, hi, lo); h[5] = hi; l[5] = lo;
        splitbf(u1.z, hi, lo); h[6] = hi; l[6] = lo;
        splitbf(u1.w, hi, lo); h[7] = hi; l[7] = lo;
        ah[kc] = h; al[kc] = l;
    }

    float psr[4] = {0.f, 0.f, 0.f, 0.f}, pdr[4] = {0.f, 0.f, 0.f, 0.f};
#pragma unroll
    for (int ct = 0; ct < 3; ++ct) {
        int n = ct * 16 + n16;
        short8 bh0, bh1, bl0, bl1;
#pragma unroll
        for (int j = 0; j < 8; ++j) {
            int k0 = q * 8 + j;
            bh0[j] = w2h[k0 * 48 + n];
            bl0[j] = w2l[k0 * 48 + n];
            bh1[j] = w2h[(32 + k0) * 48 + n];
            bl1[j] = w2l[(32 + k0) * 48 + n];
        }
        floatx4 c = {0.f, 0.f, 0.f, 0.f};
        c = __builtin_amdgcn_mfma_f32_16x16x32_bf16(ah[0], bl0, c, 0, 0, 0);
        c = __builtin_amdgcn_mfma_f32_16x16x32_bf16(al[0], bh0, c, 0, 0, 0);
        c = __builtin_amdgcn_mfma_f32_16x16x32_bf16(ah[0], bh0, c, 0, 0, 0);
        c = __builtin_amdgcn_mfma_f32_16x16x32_bf16(ah[1], bl1, c, 0, 0, 0);
        c = __builtin_amdgcn_mfma_f32_16x16x32_bf16(al[1], bh1, c, 0, 0, 0);
        c = __builtin_amdgcn_mfma_f32_16x16x32_bf16(ah[1], bh1, c, 0, 0, 0);

        int col = ct * 16 + n16;
#pragma unroll
        for (int r = 0; r < 4; ++r) {
            int row = nb + q * 4 + r;
            if (col < 40 && row < N) h2b[(size_t)row * 40 + col] = (unsigned short)f2bf(c[r]);
        }
        float asv = (col < 40) ? att_s[col] : 0.f;
        float adv = (col < 40) ? att_d[col] : 0.f;
#pragma unroll
        for (int r = 0; r < 4; ++r) {
            psr[r] = fmaf(c[r], asv, psr[r]);
            pdr[r] = fmaf(c[r], adv, pdr[r]);
        }
    }
#pragma unroll
    for (int r = 0; r < 4; ++r) {
        float ps = psr[r], pd = pdr[r];
#pragma unroll
        for (int m = 1; m < 16; m <<= 1) {
            ps += __shfl_xor(ps, m, 64);
            pd += __shfl_xor(pd, m, 64);
        }
        int row = nb + q * 4 + r;
        if (n16 == 0 && row < N) { a2s[row] = ps; a2d[row] = pd; }
    }
}

// ---------------- Layer 2 aggregation: 3 edges per gather instr + log_softmax ----------------
__global__ __launch_bounds__(256) void k_agg2(const unsigned short* __restrict__ h2b,
                                              const float* __restrict__ a2s,
                                              const float* __restrict__ a2d,
                                              const int* __restrict__ offsets,
                                              const int* __restrict__ csr_src,
                                              const float* __restrict__ b2,
                                              float* __restrict__ out, int N) {
    int wave = threadIdx.x >> 6, lane = threadIdx.x & 63;
    int d = blockIdx.x * 4 + wave;
    if (d >= N) return;
    int t = lane / 20;          // 0..2 active thirds (3 = idle tail lanes 60..63)
    int c = lane % 20;          // channel pair: 2c, 2c+1
    float ad = a2d[d];
    float w0 = lrelu_exp(a2s[d] + ad);
    float accx = 0.f, accy = 0.f;
    if (t == 0) {               // self-loop on third 0
        unsigned v = *(const unsigned*)(h2b + (size_t)d * 40 + 2 * c);
        accx = w0 * bfpair_lo(v);
        accy = w0 * bfpair_hi(v);
    }
    float wsum_l = 0.f;
    int i0 = offsets[d], i1 = offsets[d + 1];
    for (int base = i0; base < i1; base += 48) {
        int m = i1 - base; if (m > 48) m = 48;
        int sv = 0; float wv = 0.f;
        if (lane < m) {
            sv = csr_src[base + lane];
            wv = lrelu_exp(a2s[sv] + ad);
        }
        wsum_l += wv;
        for (int j = 0; j < m; j += 24) {
            int si[8]; float wq[8]; unsigned vv[8];
#pragma unroll
            for (int u = 0; u < 8; ++u) {
                int e = j + 3 * u + t;
                si[u] = __shfl(sv, e, 64);
                wq[u] = __shfl(wv, e, 64);
            }
#pragma unroll
            for (int u = 0; u < 8; ++u)
                vv[u] = *(const unsigned*)(h2b + (size_t)si[u] * 40 + 2 * c);
#pragma unroll
            for (int u = 0; u < 8; ++u) {
                accx = fmaf(wq[u], bfpair_lo(vv[u]), accx);
                accy = fmaf(wq[u], bfpair_hi(vv[u]), accy);
            }
        }
    }
    accx += __shfl(accx, lane + 20, 64) + __shfl(accx, lane + 40, 64);
    accy += __shfl(accy, lane + 20, 64) + __shfl(accy, lane + 40, 64);
#pragma unroll
    for (int mm = 1; mm < 64; mm <<= 1) wsum_l += __shfl_xor(wsum_l, mm, 64);
    float wsum = wsum_l + w0;
    bool act = (lane < 20);
    float inv = 1.f / (wsum + 1e-16f);
    float ox = act ? (accx * inv + b2[2 * c]) : -INFINITY;
    float oy = act ? (accy * inv + b2[2 * c + 1]) : -INFINITY;
    float mx = fmaxf(ox, oy);
#pragma unroll
    for (int mm = 1; mm < 64; mm <<= 1) mx = fmaxf(mx, __shfl_xor(mx, mm, 64));
    float ex = act ? (__expf(ox - mx) + __expf(oy - mx)) : 0.f;
#pragma unroll
    for (int mm = 1; mm < 64; mm <<= 1) ex += __shfl_xor(ex, mm, 64);
    if (act) {
        float lse = __logf(ex);
        float2 o2 = make_float2(ox - mx - lse, oy - mx - lse);
        *(float2*)(out + (size_t)d * 40 + 2 * c) = o2;
    }
}

// ---------------- launcher ----------------

extern "C" void kernel_launch(void* const* d_in, const int* in_sizes, int n_in,
                              void* d_out, int out_size, void* d_ws, size_t ws_size,
                              hipStream_t stream) {
    const float* x   = (const float*)d_in[0];
    const int*   ei  = (const int*)d_in[1];
    const float* W1  = (const float*)d_in[2];
    const float* as1 = (const float*)d_in[3];
    const float* ad1 = (const float*)d_in[4];
    const float* b1  = (const float*)d_in[5];
    const float* W2  = (const float*)d_in[6];
    const float* as2 = (const float*)d_in[7];
    const float* ad2 = (const float*)d_in[8];
    const float* b2  = (const float*)d_in[9];
    float* out = (float*)d_out;

    int N = in_sizes[0] / 128;   // 100000
    int E = in_sizes[1] / 2;     // 1600000
    const int* src = ei;
    const int* dst = ei + E;

    int NBUK = (N + 255) >> BSHIFT;          // 391
    int CHUNK = 4096;
    int NBLK = (E + CHUNK - 1) / CHUNK;      // 391

    char* ws = (char*)d_ws;
    size_t off = 0;
    auto alloc = [&](size_t bytes) -> char* {
        char* p = ws + off;
        off += (bytes + 255) & ~(size_t)255;
        return p;
    };
    unsigned short* h1b = (unsigned short*)alloc((size_t)N * 64 * 2);   // bf16
    float* a_s1    = (float*)alloc((size_t)N * 8 * 4);
    float* a_d1    = (float*)alloc((size_t)N * 8 * 4);
    float* y1      = (float*)alloc((size_t)N * 64 * 4);                 // fp32 (precision-critical)
    // h2b (bf16, 8 MB) and packed (uint, 6.4 MB) are temporally disjoint: share region.
    size_t shared_sz = (size_t)N * 40 * 2;
    if ((size_t)E * 4 > shared_sz) shared_sz = (size_t)E * 4;
    char*  region  = alloc(shared_sz);
    unsigned short* h2b = (unsigned short*)region;
    unsigned* packed    = (unsigned*)region;
    float* a2s     = (float*)alloc((size_t)N * 4);
    float* a2d     = (float*)alloc((size_t)N * 4);
    int*   offsets = (int*)alloc((size_t)(N + 1) * 4);
    int*   csr_src = (int*)alloc((size_t)E * 4);
    int*   blockhist  = (int*)alloc((size_t)NBUK * NBLK * 4);
    int*   btot       = (int*)alloc((size_t)NBUK * 4);
    int*   bucketbase = (int*)alloc((size_t)(NBUK + 1) * 4);
    short* w2h     = (short*)alloc((size_t)64 * 48 * 2);
    short* w2l     = (short*)alloc((size_t)64 * 48 * 2);

    int nb = (N + 3) / 4;
    int gb = (N + 63) / 64;

    k_hist<<<NBLK, 512, 0, stream>>>(dst, E, CHUNK, NBLK, NBUK, blockhist);
    k_colscan<<<NBUK, 256, 0, stream>>>(blockhist, btot, NBLK);
    k_bucket_scan<<<1, 512, 0, stream>>>(btot, bucketbase, NBUK);
    k_partition<<<NBLK, 512, 0, stream>>>(src, dst, E, CHUNK, NBLK, NBUK, blockhist,
                                          bucketbase, packed);
    k_fine<<<NBUK, 512, 0, stream>>>(packed, bucketbase, offsets, csr_src, N, NBUK);
    k_splitW2<<<12, 256, 0, stream>>>(W2, w2h, w2l);
    k_gemm1<<<gb, 256, 0, stream>>>(x, W1, as1, ad1, h1b, a_s1, a_d1, N);
    k_agg1<<<nb, 256, 0, stream>>>(h1b, a_s1, a_d1, offsets, csr_src, b1, y1, N);
    k_gemm2<<<gb, 256, 0, stream>>>(y1, w2h, w2l, as2, ad2, h2b, a2s, a2d, N);
    k_agg2<<<nb, 256, 0, stream>>>(h2b, a2s, a2d, offsets, csr_src, b2, out, N);
}